// Round 5
// baseline (173.121 us; speedup 1.0000x reference)
//
#include <hip/hip_runtime.h>
#include <math.h>

// Gaussian splatting forward rasterizer, MI355X.
// P=2048 gaussians, 128x128 image. Output: img (3*128*128 f32) ++ radii (P f32).
//
// R10: dispatch-count attack. Accounting across R8/R9 shows a fixed harness
// floor of 2x39.4us workspace-poison fills; our controllable ~25us is mostly
// 3 kernels + 3 launch boundaries. Changes vs R9 (104.2us):
//  - raster+combine fused via ticket atomic (stream-k fixup pattern): every
//    (tile,chunk) block writes its partial (per-tile-contiguous), threadfence,
//    tid0 atomicAdd ticket; the block drawing ticket KCH-1 acquires, reads all
//    16 partials, folds in exact chunk order, writes img. No spinning, no
//    co-residency assumption (deadlock-free; R7's grid.sync cost 65us/sync).
//    Tickets zeroed by prep (kernel-boundary visibility).
//  - prep: 512-thread blocks, 8 key-slices x 64 -> Phase B rank loop halves
//    to 64 uint4 iterations (prep is latency-bound at ~1 block/CU).
// Compositing arithmetic and fold order bit-identical to R9 (absmax 0.0).

#define IMG 128
#define NPIX (IMG * IMG)
#define GS 12        // record: px py ca cb cc op r g b r2 pad pad
#define SORT_N 2048
#define KCH 16
#define CHUNK (SORT_N / KCH)   // 128
#define NTILE 64

// ---------------------------------------------------------- projection chain
__device__ __forceinline__ void gproj(int i,
                                      const float* __restrict__ means,
                                      const float* __restrict__ rots,
                                      const float* __restrict__ scales,
                                      const float* __restrict__ vm,
                                      const float* __restrict__ pm,
                                      float& depth, bool& valid,
                                      float& px, float& py,
                                      float& ca, float& cb, float& cc,
                                      float& lam)
{
    const float W = (float)IMG, H = (float)IMG;
    const float tanfov = 0.5773502691896258f;        // tan(FOV/2)
    const float focal_x = W / (2.0f * tanfov);
    const float focal_y = H / (2.0f * tanfov);
    const float lim = 1.3f * tanfov;

    float mx = means[3 * i + 0], my = means[3 * i + 1], mz = means[3 * i + 2];

    float tx = vm[0] * mx + vm[1] * my + vm[2]  * mz + vm[3];
    float ty = vm[4] * mx + vm[5] * my + vm[6]  * mz + vm[7];
    float tz = vm[8] * mx + vm[9] * my + vm[10] * mz + vm[11];
    depth = tz;

    float ph0 = pm[0]  * mx + pm[1]  * my + pm[2]  * mz + pm[3];
    float ph1 = pm[4]  * mx + pm[5]  * my + pm[6]  * mz + pm[7];
    float pw  = pm[12] * mx + pm[13] * my + pm[14] * mz + pm[15];
    float rinv = 1.0f / (pw + 1e-7f);
    px = ((ph0 * rinv + 1.0f) * W - 1.0f) * 0.5f;
    py = ((ph1 * rinv + 1.0f) * H - 1.0f) * 0.5f;

    float qw = rots[4 * i + 0], qx = rots[4 * i + 1], qy = rots[4 * i + 2], qz = rots[4 * i + 3];
    float qn = sqrtf(qw * qw + qx * qx + qy * qy + qz * qz);
    qw /= qn; qx /= qn; qy /= qn; qz /= qn;
    float R00 = 1.0f - 2.0f * (qy * qy + qz * qz), R01 = 2.0f * (qx * qy - qw * qz), R02 = 2.0f * (qx * qz + qw * qy);
    float R10 = 2.0f * (qx * qy + qw * qz), R11 = 1.0f - 2.0f * (qx * qx + qz * qz), R12 = 2.0f * (qy * qz - qw * qx);
    float R20 = 2.0f * (qx * qz - qw * qy), R21 = 2.0f * (qy * qz + qw * qx), R22 = 1.0f - 2.0f * (qx * qx + qy * qy);

    float sx = scales[3 * i + 0], sy = scales[3 * i + 1], sz = scales[3 * i + 2];
    float M00 = R00 * sx, M01 = R01 * sy, M02 = R02 * sz;
    float M10 = R10 * sx, M11 = R11 * sy, M12 = R12 * sz;
    float M20 = R20 * sx, M21 = R21 * sy, M22 = R22 * sz;
    float S00 = M00 * M00 + M01 * M01 + M02 * M02;
    float S01 = M00 * M10 + M01 * M11 + M02 * M12;
    float S02 = M00 * M20 + M01 * M21 + M02 * M22;
    float S11 = M10 * M10 + M11 * M11 + M12 * M12;
    float S12 = M10 * M20 + M11 * M21 + M12 * M22;
    float S22 = M20 * M20 + M21 * M21 + M22 * M22;

    float txc = fminf(fmaxf(tx / tz, -lim), lim) * tz;
    float tyc = fminf(fmaxf(ty / tz, -lim), lim) * tz;
    float J00 = focal_x / tz, J02 = -focal_x * txc / (tz * tz);
    float J11 = focal_y / tz, J12 = -focal_y * tyc / (tz * tz);

    float T00 = J00 * vm[0] + J02 * vm[8];
    float T01 = J00 * vm[1] + J02 * vm[9];
    float T02 = J00 * vm[2] + J02 * vm[10];
    float T10 = J11 * vm[4] + J12 * vm[8];
    float T11 = J11 * vm[5] + J12 * vm[9];
    float T12 = J11 * vm[6] + J12 * vm[10];

    float U00 = T00 * S00 + T01 * S01 + T02 * S02;
    float U01 = T00 * S01 + T01 * S11 + T02 * S12;
    float U02 = T00 * S02 + T01 * S12 + T02 * S22;
    float U10 = T10 * S00 + T11 * S01 + T12 * S02;
    float U11 = T10 * S01 + T11 * S11 + T12 * S12;
    float U12 = T10 * S02 + T11 * S12 + T12 * S22;
    float C00 = U00 * T00 + U01 * T01 + U02 * T02;
    float C01 = U00 * T10 + U01 * T11 + U02 * T12;
    float C11 = U10 * T10 + U11 * T11 + U12 * T12;

    float a = C00 + 0.3f, b = C01, c = C11 + 0.3f;
    float det = a * c - b * b;
    valid = (depth > 0.2f) && (det > 0.0f);
    float det_s = valid ? det : 1.0f;
    ca = c / det_s; cb = -b / det_s; cc = a / det_s;

    float mid = 0.5f * (a + c);
    lam = mid + sqrtf(fmaxf(mid * mid - det, 0.1f));
}

// ------------------------------------------- fused preprocess + rank + scatter
// 512 threads: 8 key-slices x 64 gaussians -> Phase B is 64 uint4 iterations.
__global__ void __launch_bounds__(512)
gsplat_prep_rank_scatter(const float* __restrict__ means,
                         const float* __restrict__ feats,
                         const float* __restrict__ ops,
                         const float* __restrict__ scales,
                         const float* __restrict__ rots,
                         const float* __restrict__ vm,
                         const float* __restrict__ pm,
                         float* __restrict__ gS,
                         float4* __restrict__ culls,
                         float* __restrict__ radii_out,
                         unsigned int* __restrict__ tickets,
                         int P)
{
    __shared__ unsigned int sk[SORT_N];
    __shared__ int partial[512];
    int tid = threadIdx.x;

    // Zero the raster's per-tile tickets (visible at next kernel boundary).
    if (blockIdx.x == 0 && tid < NTILE) tickets[tid] = 0u;

    // Phase A: depth-only sort keys. valid == depth>0.2 (det>0 always:
    // det = (C00+.3)(C11+.3)-C01^2 >= .3(C00+C11)+.09, cov2d PSD; margin
    // ~1e3 vs fp32 error ~1e-3 -- holds in the reference too).
    #pragma unroll 2
    for (int j = tid; j < SORT_N; j += 512) {
        unsigned int key = 0xFFFFFFFFu;                  // pad sorts last
        if (j < P) {
            float mx = means[3 * j + 0], my = means[3 * j + 1], mz = means[3 * j + 2];
            float tz = vm[8] * mx + vm[9] * my + vm[10] * mz + vm[11];
            key = (tz > 0.2f) ? __float_as_uint(tz) : 0x7f800000u; // +inf invalid
        }
        sk[j] = key;
    }
    __syncthreads();

    // Phase B: stable rank for this block's 64 gaussians (8 key-slices x 64).
    int g = tid & 63, s = tid >> 6;                      // s in [0,8)
    int i = blockIdx.x * 64 + g;
    bool act = (i < P);
    unsigned int ki = act ? sk[i] : 0u;

    const int SLICE = SORT_N / 8;                        // 256
    int j0 = s * SLICE;
    const uint4* sk4 = (const uint4*)(sk + j0);
    int r = 0;
    #pragma unroll 4
    for (int q = 0; q < SLICE / 4; ++q) {                // 64 iterations
        uint4 k = sk4[q];                                // wave-broadcast
        int j = j0 + 4 * q;
        r += (k.x < ki) || (k.x == ki && (j + 0) < i);
        r += (k.y < ki) || (k.y == ki && (j + 1) < i);
        r += (k.z < ki) || (k.z == ki && (j + 2) < i);
        r += (k.w < ki) || (k.w == ki && (j + 3) < i);
    }
    partial[tid] = r;
    __syncthreads();

    // Phase C: full record for own gaussian -> sorted slot; radii in orig order.
    if (s == 0 && act) {
        int rank = 0;
        #pragma unroll
        for (int k = 0; k < 8; ++k) rank += partial[64 * k + g];

        float depth, px, py, ca, cb, cc, lam; bool valid;
        gproj(i, means, rots, scales, vm, pm, depth, valid, px, py, ca, cb, cc, lam);

        const float SH_C0 = 0.28209479177387814f;
        float colr = fmaxf(SH_C0 * feats[3 * i + 0] + 0.5f, 0.0f);
        float colg = fmaxf(SH_C0 * feats[3 * i + 1] + 0.5f, 0.0f);
        float colb = fmaxf(SH_C0 * feats[3 * i + 2] + 0.5f, 0.0f);

        float opv = ops[i];
        float r2;
        if (valid) {
            // alpha >= 1/255 requires d^2 <= 2*lam_max*ln(255*op) (exact bound)
            r2 = 2.0f * lam * __logf(255.0f * opv) * 1.02f + 0.5f;
        } else {
            px = 0.0f; py = 0.0f; ca = 0.0f; cb = 0.0f; cc = 0.0f;
            opv = 0.0f; r2 = -1.0f;                      // never composited
        }
        radii_out[i] = valid ? ceilf(3.0f * sqrtf(lam)) : 0.0f;

        float4* dst = (float4*)(gS + (size_t)rank * GS);
        dst[0] = make_float4(px, py, ca, cb);
        dst[1] = make_float4(cc, opv, colr, colg);
        dst[2] = make_float4(colb, r2, 0.0f, 0.0f);
        culls[rank] = make_float4(px, py, r2, 0.0f);     // compact cull record
    }
}

// ------------------------------------------------- raster + fused combine
// Block = (tile, chunk): 64 tiles x KCH=16 chunks = 1024 blocks (4/CU).
// Wave-parallel ballot cull + 4-wide unrolled bit-loop (R9). Then: write
// partial to per-tile slab, threadfence, ticket atomicAdd; the block drawing
// ticket KCH-1 reads all 16 partials and folds them in exact chunk order.
__global__ void __launch_bounds__(256, 4)
gsplat_raster_fused(const float* __restrict__ gS,
                    const float4* __restrict__ culls,
                    int P, float4* __restrict__ part,
                    unsigned int* __restrict__ tickets,
                    float* __restrict__ img)
{
    int tid = threadIdx.x;
    int lx = tid & 15, ly = tid >> 4;
    int lane = tid & 63;
    int tile = blockIdx.x;
    int kc = blockIdx.y;
    int tilex = tile & 7, tiley = tile >> 3;
    int x = tilex * 16 + lx, y = tiley * 16 + ly;
    float gx = (float)x, gy = (float)y;
    float tx0 = (float)(tilex * 16), tx1 = (float)(tilex * 16 + 15);
    float ty0 = (float)(tiley * 16), ty1 = (float)(tiley * 16 + 15);

    int base = kc * CHUNK;
    int cnt = min(CHUNK, P - base);

    float T = 1.0f, cr = 0.0f, cg = 0.0f, cb = 0.0f;
    const float* Gp = gS + (size_t)base * GS;

    // Both cull loads issue immediately (independent).
    float4 cu0 = culls[base + lane];
    float4 cu1 = culls[base + 64 + lane];

    #pragma unroll
    for (int half = 0; half < 2; ++half) {
        int h = half * 64;
        float4 cu = (half == 0) ? cu0 : cu1;
        bool pred = false;
        if (h + lane < cnt) {
            float ddx = cu.x - fminf(fmaxf(cu.x, tx0), tx1);
            float ddy = cu.y - fminf(fmaxf(cu.y, ty0), ty1);
            pred = (ddx * ddx + ddy * ddy <= cu.z);
        }
        unsigned long long m = __ballot(pred);           // wave-uniform mask
        while (m) {
            int b0 = __builtin_ctzll(m); m &= m - 1;
            int n = 1, b1 = b0, b2 = b0, b3 = b0;
            if (m) { b1 = __builtin_ctzll(m); m &= m - 1; n = 2;
                if (m) { b2 = __builtin_ctzll(m); m &= m - 1; n = 3;
                    if (m) { b3 = __builtin_ctzll(m); m &= m - 1; n = 4; } } }

            const float4* R0 = (const float4*)(Gp + (size_t)(h + b0) * GS);
            const float4* R1 = (const float4*)(Gp + (size_t)(h + b1) * GS);
            const float4* R2 = (const float4*)(Gp + (size_t)(h + b2) * GS);
            const float4* R3 = (const float4*)(Gp + (size_t)(h + b3) * GS);
            float4 A0 = R0[0], B0 = R0[1], C0 = R0[2];
            float4 A1 = R1[0], B1 = R1[1], C1 = R1[2];
            float4 A2 = R2[0], B2 = R2[1], C2 = R2[2];
            float4 A3 = R3[0], B3 = R3[1], C3 = R3[2];

            float dx0 = gx - A0.x, dy0 = gy - A0.y;
            float p0 = -0.5f * (A0.z * dx0 * dx0 + B0.x * dy0 * dy0) - A0.w * dx0 * dy0;
            float a0 = fminf(0.99f, B0.y * __expf(fminf(p0, 0.0f)));
            a0 = (p0 > 0.0f) ? 0.0f : a0;
            a0 = (a0 < 0.00392156862745098f) ? 0.0f : a0;

            float dx1 = gx - A1.x, dy1 = gy - A1.y;
            float p1 = -0.5f * (A1.z * dx1 * dx1 + B1.x * dy1 * dy1) - A1.w * dx1 * dy1;
            float a1 = fminf(0.99f, B1.y * __expf(fminf(p1, 0.0f)));
            a1 = (p1 > 0.0f) ? 0.0f : a1;
            a1 = (a1 < 0.00392156862745098f) ? 0.0f : a1;

            float dx2 = gx - A2.x, dy2 = gy - A2.y;
            float p2 = -0.5f * (A2.z * dx2 * dx2 + B2.x * dy2 * dy2) - A2.w * dx2 * dy2;
            float a2 = fminf(0.99f, B2.y * __expf(fminf(p2, 0.0f)));
            a2 = (p2 > 0.0f) ? 0.0f : a2;
            a2 = (a2 < 0.00392156862745098f) ? 0.0f : a2;

            float dx3 = gx - A3.x, dy3 = gy - A3.y;
            float p3 = -0.5f * (A3.z * dx3 * dx3 + B3.x * dy3 * dy3) - A3.w * dx3 * dy3;
            float a3 = fminf(0.99f, B3.y * __expf(fminf(p3, 0.0f)));
            a3 = (p3 > 0.0f) ? 0.0f : a3;
            a3 = (a3 < 0.00392156862745098f) ? 0.0f : a3;

            float w;
            w = T * a0; cr = fmaf(w, B0.z, cr); cg = fmaf(w, B0.w, cg); cb = fmaf(w, C0.x, cb); T *= (1.0f - a0);
            if (n > 1) { w = T * a1; cr = fmaf(w, B1.z, cr); cg = fmaf(w, B1.w, cg); cb = fmaf(w, C1.x, cb); T *= (1.0f - a1); }
            if (n > 2) { w = T * a2; cr = fmaf(w, B2.z, cr); cg = fmaf(w, B2.w, cg); cb = fmaf(w, C2.x, cb); T *= (1.0f - a2); }
            if (n > 3) { w = T * a3; cr = fmaf(w, B3.z, cr); cg = fmaf(w, B3.w, cg); cb = fmaf(w, C3.x, cb); T *= (1.0f - a3); }
        }
    }

    // ---- partial write (per-tile-contiguous slab) + release ticket
    float4* slab = part + ((size_t)tile * KCH) * 256;
    slab[kc * 256 + tid] = make_float4(cr, cg, cb, T);
    __threadfence();                                     // my store visible
    __syncthreads();                                     // whole block done
    __shared__ unsigned int s_old;
    if (tid == 0) s_old = atomicAdd(&tickets[tile], 1u); // device-scope
    __syncthreads();

    if (s_old == KCH - 1) {
        __threadfence();                                 // acquire side
        // Fold the 16 partials in exact chunk order (8+8 to bound VGPRs).
        float4 v[8];
        float Tt = 1.0f, r = 0.0f, g = 0.0f, b = 0.0f;
        #pragma unroll
        for (int c = 0; c < 8; ++c) v[c] = slab[c * 256 + tid];
        #pragma unroll
        for (int c = 0; c < 8; ++c) {
            r = fmaf(Tt, v[c].x, r);
            g = fmaf(Tt, v[c].y, g);
            b = fmaf(Tt, v[c].z, b);
            Tt *= v[c].w;
        }
        #pragma unroll
        for (int c = 0; c < 8; ++c) v[c] = slab[(8 + c) * 256 + tid];
        #pragma unroll
        for (int c = 0; c < 8; ++c) {
            r = fmaf(Tt, v[c].x, r);
            g = fmaf(Tt, v[c].y, g);
            b = fmaf(Tt, v[c].z, b);
            Tt *= v[c].w;
        }
        int pix = y * IMG + x;
        img[pix]            = r + Tt;
        img[NPIX + pix]     = g + Tt;
        img[2 * NPIX + pix] = b + Tt;
    }
}

// ------------------------------------------------------------------ launch
extern "C" void kernel_launch(void* const* d_in, const int* in_sizes, int n_in,
                              void* d_out, int out_size, void* d_ws, size_t ws_size,
                              hipStream_t stream)
{
    const float* means  = (const float*)d_in[0];
    const float* feats  = (const float*)d_in[2];
    const float* ops    = (const float*)d_in[3];
    const float* scales = (const float*)d_in[4];
    const float* rots   = (const float*)d_in[5];
    const float* vm     = (const float*)d_in[6];
    const float* pm     = (const float*)d_in[7];

    int P = in_sizes[0] / 3;   // 2048

    float* img   = (float*)d_out;            // 3*128*128
    float* radii = (float*)d_out + 3 * NPIX; // P

    float*        gS      = (float*)d_ws;                         // 96 KB
    float4*       culls   = (float4*)(gS + (size_t)SORT_N * GS);  // 32 KB
    float4*       part    = culls + SORT_N;                       // 4 MB
    unsigned int* tickets = (unsigned int*)(part + (size_t)NTILE * KCH * 256);

    gsplat_prep_rank_scatter<<<(P + 63) / 64, 512, 0, stream>>>(
        means, feats, ops, scales, rots, vm, pm, gS, culls, radii, tickets, P);

    gsplat_raster_fused<<<dim3(NTILE, KCH), 256, 0, stream>>>(
        gS, culls, P, part, tickets, img);
}

// Round 7
// 95.612 us; speedup vs baseline: 1.8107x; 1.8107x over previous
//
#include <hip/hip_runtime.h>
#include <math.h>

// Gaussian splatting forward rasterizer, MI355X.
// P=2048 gaussians, 128x128 image. Output: img (3*128*128 f32) ++ radii (P f32).
//
// R12 == R11 resubmit (R11 bench died with "container failed twice" -- a
// broker/infra failure, not a pytest failure; the kernel has no spin, no
// grid sync, no OOB, and terminates unconditionally).
// Design: R10's ticket-fusion (raster+combine in one dispatch) with the
// coherence mechanism fixed: partials are written WRITE-THROUGH with
// system-scope relaxed atomic stores (sc0+sc1: bypass the non-coherent
// per-XCD L2, land at the device-coherent point). Visibility needs only
// s_waitcnt vmcnt(0) -- no L2 writeback (R10's __threadfence cost ~90us).
// Ticket = relaxed system-scope fetch_add; the block drawing ticket KCH-1
// reads the 16 partials with system-scope loads (LLC) and folds them in
// exact chunk order. Raster loop verbatim R9 (104.2us best); prep is R10's
// 512-thread variant (8 key-slices -> Phase B halved).

#define IMG 128
#define NPIX (IMG * IMG)
#define GS 12        // record: px py ca cb cc op r g b r2 pad pad
#define SORT_N 2048
#define KCH 16
#define CHUNK (SORT_N / KCH)   // 128
#define NTILE 64

typedef unsigned long long u64;

// -------- system-scope (write-through, L2-bypassing) 16B helpers
__device__ __forceinline__ void sysStore4(float4* p, float4 v)
{
    union { float f[2]; u64 u; } lo, hi;
    lo.f[0] = v.x; lo.f[1] = v.y; hi.f[0] = v.z; hi.f[1] = v.w;
    u64* q = (u64*)p;
    __hip_atomic_store(q,     lo.u, __ATOMIC_RELAXED, __HIP_MEMORY_SCOPE_SYSTEM);
    __hip_atomic_store(q + 1, hi.u, __ATOMIC_RELAXED, __HIP_MEMORY_SCOPE_SYSTEM);
}
__device__ __forceinline__ float4 sysLoad4(const float4* p)
{
    const u64* q = (const u64*)p;
    u64 a = __hip_atomic_load(q,     __ATOMIC_RELAXED, __HIP_MEMORY_SCOPE_SYSTEM);
    u64 b = __hip_atomic_load(q + 1, __ATOMIC_RELAXED, __HIP_MEMORY_SCOPE_SYSTEM);
    union { u64 u; float f[2]; } lo, hi;
    lo.u = a; hi.u = b;
    return make_float4(lo.f[0], lo.f[1], hi.f[0], hi.f[1]);
}

// ---------------------------------------------------------- projection chain
__device__ __forceinline__ void gproj(int i,
                                      const float* __restrict__ means,
                                      const float* __restrict__ rots,
                                      const float* __restrict__ scales,
                                      const float* __restrict__ vm,
                                      const float* __restrict__ pm,
                                      float& depth, bool& valid,
                                      float& px, float& py,
                                      float& ca, float& cb, float& cc,
                                      float& lam)
{
    const float W = (float)IMG, H = (float)IMG;
    const float tanfov = 0.5773502691896258f;        // tan(FOV/2)
    const float focal_x = W / (2.0f * tanfov);
    const float focal_y = H / (2.0f * tanfov);
    const float lim = 1.3f * tanfov;

    float mx = means[3 * i + 0], my = means[3 * i + 1], mz = means[3 * i + 2];

    float tx = vm[0] * mx + vm[1] * my + vm[2]  * mz + vm[3];
    float ty = vm[4] * mx + vm[5] * my + vm[6]  * mz + vm[7];
    float tz = vm[8] * mx + vm[9] * my + vm[10] * mz + vm[11];
    depth = tz;

    float ph0 = pm[0]  * mx + pm[1]  * my + pm[2]  * mz + pm[3];
    float ph1 = pm[4]  * mx + pm[5]  * my + pm[6]  * mz + pm[7];
    float pw  = pm[12] * mx + pm[13] * my + pm[14] * mz + pm[15];
    float rinv = 1.0f / (pw + 1e-7f);
    px = ((ph0 * rinv + 1.0f) * W - 1.0f) * 0.5f;
    py = ((ph1 * rinv + 1.0f) * H - 1.0f) * 0.5f;

    float qw = rots[4 * i + 0], qx = rots[4 * i + 1], qy = rots[4 * i + 2], qz = rots[4 * i + 3];
    float qn = sqrtf(qw * qw + qx * qx + qy * qy + qz * qz);
    qw /= qn; qx /= qn; qy /= qn; qz /= qn;
    float R00 = 1.0f - 2.0f * (qy * qy + qz * qz), R01 = 2.0f * (qx * qy - qw * qz), R02 = 2.0f * (qx * qz + qw * qy);
    float R10 = 2.0f * (qx * qy + qw * qz), R11 = 1.0f - 2.0f * (qx * qx + qz * qz), R12 = 2.0f * (qy * qz - qw * qx);
    float R20 = 2.0f * (qx * qz - qw * qy), R21 = 2.0f * (qy * qz + qw * qx), R22 = 1.0f - 2.0f * (qx * qx + qy * qy);

    float sx = scales[3 * i + 0], sy = scales[3 * i + 1], sz = scales[3 * i + 2];
    float M00 = R00 * sx, M01 = R01 * sy, M02 = R02 * sz;
    float M10 = R10 * sx, M11 = R11 * sy, M12 = R12 * sz;
    float M20 = R20 * sx, M21 = R21 * sy, M22 = R22 * sz;
    float S00 = M00 * M00 + M01 * M01 + M02 * M02;
    float S01 = M00 * M10 + M01 * M11 + M02 * M12;
    float S02 = M00 * M20 + M01 * M21 + M02 * M22;
    float S11 = M10 * M10 + M11 * M11 + M12 * M12;
    float S12 = M10 * M20 + M11 * M21 + M12 * M22;
    float S22 = M20 * M20 + M21 * M21 + M22 * M22;

    float txc = fminf(fmaxf(tx / tz, -lim), lim) * tz;
    float tyc = fminf(fmaxf(ty / tz, -lim), lim) * tz;
    float J00 = focal_x / tz, J02 = -focal_x * txc / (tz * tz);
    float J11 = focal_y / tz, J12 = -focal_y * tyc / (tz * tz);

    float T00 = J00 * vm[0] + J02 * vm[8];
    float T01 = J00 * vm[1] + J02 * vm[9];
    float T02 = J00 * vm[2] + J02 * vm[10];
    float T10 = J11 * vm[4] + J12 * vm[8];
    float T11 = J11 * vm[5] + J12 * vm[9];
    float T12 = J11 * vm[6] + J12 * vm[10];

    float U00 = T00 * S00 + T01 * S01 + T02 * S02;
    float U01 = T00 * S01 + T01 * S11 + T02 * S12;
    float U02 = T00 * S02 + T01 * S12 + T02 * S22;
    float U10 = T10 * S00 + T11 * S01 + T12 * S02;
    float U11 = T10 * S01 + T11 * S11 + T12 * S12;
    float U12 = T10 * S02 + T11 * S12 + T12 * S22;
    float C00 = U00 * T00 + U01 * T01 + U02 * T02;
    float C01 = U00 * T10 + U01 * T11 + U02 * T12;
    float C11 = U10 * T10 + U11 * T11 + U12 * T12;

    float a = C00 + 0.3f, b = C01, c = C11 + 0.3f;
    float det = a * c - b * b;
    valid = (depth > 0.2f) && (det > 0.0f);
    float det_s = valid ? det : 1.0f;
    ca = c / det_s; cb = -b / det_s; cc = a / det_s;

    float mid = 0.5f * (a + c);
    lam = mid + sqrtf(fmaxf(mid * mid - det, 0.1f));
}

// ------------------------------------------- fused preprocess + rank + scatter
// 512 threads: 8 key-slices x 64 gaussians -> Phase B is 64 uint4 iterations.
__global__ void __launch_bounds__(512)
gsplat_prep_rank_scatter(const float* __restrict__ means,
                         const float* __restrict__ feats,
                         const float* __restrict__ ops,
                         const float* __restrict__ scales,
                         const float* __restrict__ rots,
                         const float* __restrict__ vm,
                         const float* __restrict__ pm,
                         float* __restrict__ gS,
                         float4* __restrict__ culls,
                         float* __restrict__ radii_out,
                         unsigned int* __restrict__ tickets,
                         int P)
{
    __shared__ unsigned int sk[SORT_N];
    __shared__ int partial[512];
    int tid = threadIdx.x;

    // Zero the raster's per-tile tickets (kernel boundary gives visibility).
    if (blockIdx.x == 0 && tid < NTILE) tickets[tid] = 0u;

    // Phase A: depth-only sort keys. valid == depth>0.2 (det>0 always:
    // det = (C00+.3)(C11+.3)-C01^2 >= .3(C00+C11)+.09, cov2d PSD; margin
    // ~1e3 vs fp32 error ~1e-3 -- holds in the reference too).
    #pragma unroll 2
    for (int j = tid; j < SORT_N; j += 512) {
        unsigned int key = 0xFFFFFFFFu;                  // pad sorts last
        if (j < P) {
            float mx = means[3 * j + 0], my = means[3 * j + 1], mz = means[3 * j + 2];
            float tz = vm[8] * mx + vm[9] * my + vm[10] * mz + vm[11];
            key = (tz > 0.2f) ? __float_as_uint(tz) : 0x7f800000u; // +inf invalid
        }
        sk[j] = key;
    }
    __syncthreads();

    // Phase B: stable rank for this block's 64 gaussians (8 key-slices x 64).
    int g = tid & 63, s = tid >> 6;                      // s in [0,8)
    int i = blockIdx.x * 64 + g;
    bool act = (i < P);
    unsigned int ki = act ? sk[i] : 0u;

    const int SLICE = SORT_N / 8;                        // 256
    int j0 = s * SLICE;
    const uint4* sk4 = (const uint4*)(sk + j0);
    int r = 0;
    #pragma unroll 4
    for (int q = 0; q < SLICE / 4; ++q) {                // 64 iterations
        uint4 k = sk4[q];                                // wave-broadcast
        int j = j0 + 4 * q;
        r += (k.x < ki) || (k.x == ki && (j + 0) < i);
        r += (k.y < ki) || (k.y == ki && (j + 1) < i);
        r += (k.z < ki) || (k.z == ki && (j + 2) < i);
        r += (k.w < ki) || (k.w == ki && (j + 3) < i);
    }
    partial[tid] = r;
    __syncthreads();

    // Phase C: full record for own gaussian -> sorted slot; radii in orig order.
    if (s == 0 && act) {
        int rank = 0;
        #pragma unroll
        for (int k = 0; k < 8; ++k) rank += partial[64 * k + g];

        float depth, px, py, ca, cb, cc, lam; bool valid;
        gproj(i, means, rots, scales, vm, pm, depth, valid, px, py, ca, cb, cc, lam);

        const float SH_C0 = 0.28209479177387814f;
        float colr = fmaxf(SH_C0 * feats[3 * i + 0] + 0.5f, 0.0f);
        float colg = fmaxf(SH_C0 * feats[3 * i + 1] + 0.5f, 0.0f);
        float colb = fmaxf(SH_C0 * feats[3 * i + 2] + 0.5f, 0.0f);

        float opv = ops[i];
        float r2;
        if (valid) {
            // alpha >= 1/255 requires d^2 <= 2*lam_max*ln(255*op) (exact bound)
            r2 = 2.0f * lam * __logf(255.0f * opv) * 1.02f + 0.5f;
        } else {
            px = 0.0f; py = 0.0f; ca = 0.0f; cb = 0.0f; cc = 0.0f;
            opv = 0.0f; r2 = -1.0f;                      // never composited
        }
        radii_out[i] = valid ? ceilf(3.0f * sqrtf(lam)) : 0.0f;

        float4* dst = (float4*)(gS + (size_t)rank * GS);
        dst[0] = make_float4(px, py, ca, cb);
        dst[1] = make_float4(cc, opv, colr, colg);
        dst[2] = make_float4(colb, r2, 0.0f, 0.0f);
        culls[rank] = make_float4(px, py, r2, 0.0f);     // compact cull record
    }
}

// ------------------------------------------------- raster + fused combine
// Block = (tile, chunk): 64 tiles x KCH=16 chunks = 1024 blocks (4/CU).
// R9's ballot cull + 4-wide unrolled bit-loop. Epilogue: partial written
// WRITE-THROUGH (system-scope relaxed stores, no L2 flush), s_waitcnt
// vmcnt(0), ticket fetch_add; block drawing ticket KCH-1 folds all 16
// partials (system-scope loads from LLC) in exact chunk order.
__global__ void __launch_bounds__(256, 4)
gsplat_raster_fused(const float* __restrict__ gS,
                    const float4* __restrict__ culls,
                    int P, float4* __restrict__ part,
                    unsigned int* __restrict__ tickets,
                    float* __restrict__ img)
{
    int tid = threadIdx.x;
    int lx = tid & 15, ly = tid >> 4;
    int lane = tid & 63;
    int tile = blockIdx.x;
    int kc = blockIdx.y;
    int tilex = tile & 7, tiley = tile >> 3;
    int x = tilex * 16 + lx, y = tiley * 16 + ly;
    float gx = (float)x, gy = (float)y;
    float tx0 = (float)(tilex * 16), tx1 = (float)(tilex * 16 + 15);
    float ty0 = (float)(tiley * 16), ty1 = (float)(tiley * 16 + 15);

    int base = kc * CHUNK;
    int cnt = min(CHUNK, P - base);

    float T = 1.0f, cr = 0.0f, cg = 0.0f, cb = 0.0f;
    const float* Gp = gS + (size_t)base * GS;

    // Both cull loads issue immediately (independent).
    float4 cu0 = culls[base + lane];
    float4 cu1 = culls[base + 64 + lane];

    #pragma unroll
    for (int half = 0; half < 2; ++half) {
        int h = half * 64;
        float4 cu = (half == 0) ? cu0 : cu1;
        bool pred = false;
        if (h + lane < cnt) {
            float ddx = cu.x - fminf(fmaxf(cu.x, tx0), tx1);
            float ddy = cu.y - fminf(fmaxf(cu.y, ty0), ty1);
            pred = (ddx * ddx + ddy * ddy <= cu.z);
        }
        unsigned long long m = __ballot(pred);           // wave-uniform mask
        while (m) {
            int b0 = __builtin_ctzll(m); m &= m - 1;
            int n = 1, b1 = b0, b2 = b0, b3 = b0;
            if (m) { b1 = __builtin_ctzll(m); m &= m - 1; n = 2;
                if (m) { b2 = __builtin_ctzll(m); m &= m - 1; n = 3;
                    if (m) { b3 = __builtin_ctzll(m); m &= m - 1; n = 4; } } }

            const float4* R0 = (const float4*)(Gp + (size_t)(h + b0) * GS);
            const float4* R1 = (const float4*)(Gp + (size_t)(h + b1) * GS);
            const float4* R2 = (const float4*)(Gp + (size_t)(h + b2) * GS);
            const float4* R3 = (const float4*)(Gp + (size_t)(h + b3) * GS);
            float4 A0 = R0[0], B0 = R0[1], C0 = R0[2];
            float4 A1 = R1[0], B1 = R1[1], C1 = R1[2];
            float4 A2 = R2[0], B2 = R2[1], C2 = R2[2];
            float4 A3 = R3[0], B3 = R3[1], C3 = R3[2];

            float dx0 = gx - A0.x, dy0 = gy - A0.y;
            float p0 = -0.5f * (A0.z * dx0 * dx0 + B0.x * dy0 * dy0) - A0.w * dx0 * dy0;
            float a0 = fminf(0.99f, B0.y * __expf(fminf(p0, 0.0f)));
            a0 = (p0 > 0.0f) ? 0.0f : a0;
            a0 = (a0 < 0.00392156862745098f) ? 0.0f : a0;

            float dx1 = gx - A1.x, dy1 = gy - A1.y;
            float p1 = -0.5f * (A1.z * dx1 * dx1 + B1.x * dy1 * dy1) - A1.w * dx1 * dy1;
            float a1 = fminf(0.99f, B1.y * __expf(fminf(p1, 0.0f)));
            a1 = (p1 > 0.0f) ? 0.0f : a1;
            a1 = (a1 < 0.00392156862745098f) ? 0.0f : a1;

            float dx2 = gx - A2.x, dy2 = gy - A2.y;
            float p2 = -0.5f * (A2.z * dx2 * dx2 + B2.x * dy2 * dy2) - A2.w * dx2 * dy2;
            float a2 = fminf(0.99f, B2.y * __expf(fminf(p2, 0.0f)));
            a2 = (p2 > 0.0f) ? 0.0f : a2;
            a2 = (a2 < 0.00392156862745098f) ? 0.0f : a2;

            float dx3 = gx - A3.x, dy3 = gy - A3.y;
            float p3 = -0.5f * (A3.z * dx3 * dx3 + B3.x * dy3 * dy3) - A3.w * dx3 * dy3;
            float a3 = fminf(0.99f, B3.y * __expf(fminf(p3, 0.0f)));
            a3 = (p3 > 0.0f) ? 0.0f : a3;
            a3 = (a3 < 0.00392156862745098f) ? 0.0f : a3;

            float w;
            w = T * a0; cr = fmaf(w, B0.z, cr); cg = fmaf(w, B0.w, cg); cb = fmaf(w, C0.x, cb); T *= (1.0f - a0);
            if (n > 1) { w = T * a1; cr = fmaf(w, B1.z, cr); cg = fmaf(w, B1.w, cg); cb = fmaf(w, C1.x, cb); T *= (1.0f - a1); }
            if (n > 2) { w = T * a2; cr = fmaf(w, B2.z, cr); cg = fmaf(w, B2.w, cg); cb = fmaf(w, C2.x, cb); T *= (1.0f - a2); }
            if (n > 3) { w = T * a3; cr = fmaf(w, B3.z, cr); cg = fmaf(w, B3.w, cg); cb = fmaf(w, C3.x, cb); T *= (1.0f - a3); }
        }
    }

    // ---- write-through partial + ticket release (no cache flush)
    float4* slab = part + ((size_t)tile * KCH) * 256;
    sysStore4(&slab[kc * 256 + tid], make_float4(cr, cg, cb, T));
    asm volatile("s_waitcnt vmcnt(0)" ::: "memory");     // stores at LLC
    __syncthreads();                                     // whole block done
    __shared__ unsigned int s_old;
    if (tid == 0)
        s_old = __hip_atomic_fetch_add(&tickets[tile], 1u,
                                       __ATOMIC_RELAXED, __HIP_MEMORY_SCOPE_SYSTEM);
    __syncthreads();

    if (s_old == KCH - 1) {
        // All 16 partials are at the coherent point; fold in chunk order.
        float4 v[8];
        float Tt = 1.0f, r = 0.0f, g = 0.0f, b = 0.0f;
        #pragma unroll
        for (int c = 0; c < 8; ++c) v[c] = sysLoad4(&slab[c * 256 + tid]);
        #pragma unroll
        for (int c = 0; c < 8; ++c) {
            r = fmaf(Tt, v[c].x, r);
            g = fmaf(Tt, v[c].y, g);
            b = fmaf(Tt, v[c].z, b);
            Tt *= v[c].w;
        }
        #pragma unroll
        for (int c = 0; c < 8; ++c) v[c] = sysLoad4(&slab[(8 + c) * 256 + tid]);
        #pragma unroll
        for (int c = 0; c < 8; ++c) {
            r = fmaf(Tt, v[c].x, r);
            g = fmaf(Tt, v[c].y, g);
            b = fmaf(Tt, v[c].z, b);
            Tt *= v[c].w;
        }
        int pix = y * IMG + x;
        img[pix]            = r + Tt;
        img[NPIX + pix]     = g + Tt;
        img[2 * NPIX + pix] = b + Tt;
    }
}

// ------------------------------------------------------------------ launch
extern "C" void kernel_launch(void* const* d_in, const int* in_sizes, int n_in,
                              void* d_out, int out_size, void* d_ws, size_t ws_size,
                              hipStream_t stream)
{
    const float* means  = (const float*)d_in[0];
    const float* feats  = (const float*)d_in[2];
    const float* ops    = (const float*)d_in[3];
    const float* scales = (const float*)d_in[4];
    const float* rots   = (const float*)d_in[5];
    const float* vm     = (const float*)d_in[6];
    const float* pm     = (const float*)d_in[7];

    int P = in_sizes[0] / 3;   // 2048

    float* img   = (float*)d_out;            // 3*128*128
    float* radii = (float*)d_out + 3 * NPIX; // P

    float*        gS      = (float*)d_ws;                         // 96 KB
    float4*       culls   = (float4*)(gS + (size_t)SORT_N * GS);  // 32 KB
    float4*       part    = culls + SORT_N;                       // 4 MB
    unsigned int* tickets = (unsigned int*)(part + (size_t)NTILE * KCH * 256);

    gsplat_prep_rank_scatter<<<(P + 63) / 64, 512, 0, stream>>>(
        means, feats, ops, scales, rots, vm, pm, gS, culls, radii, tickets, P);

    gsplat_raster_fused<<<dim3(NTILE, KCH), 256, 0, stream>>>(
        gS, culls, P, part, tickets, img);
}